// Round 11
// baseline (57.563 us; speedup 1.0000x reference)
//
#include <hip/hip_runtime.h>
#include <hip/hip_bf16.h>

// EnhancedBCMLayer: block-circulant matmul == dense GEMM
//   out = X (4096x2048) @ W^T (2048x2048) + b, fp32 out
//   W[f*16+t][g*16+u] = iv[f, g, (t-u)&15]
// THIS ROUND: restore cross-block overlap (m97's real mechanism).
// BM=128 x BN=128 x BK=64, grid 512 = 2 blocks/CU, 4 waves (2Mx2N),
// per-wave 64x64, 16x16x32 MFMA. LDS 64 KB = 2 buffers x (A 16K + B 16K).
// Per tile: LDA kc0 | stage t+1 (8 GLD) | MFMA | LDA kc1 | MFMA | vmcnt(0) | BAR
// (1 barrier/tile; drain covered by the co-resident block). T1+T2+T5.

#define M_DIM 4096
#define N_DIM 2048
#define K_DIM 2048
#define BK 64
#define NT (K_DIM / BK)   // 32 K-tiles
#define BUFSZ 32768       // 32 KB: A [128 rows][128B] + B [128 rows][128B] at +16384

typedef __attribute__((ext_vector_type(8))) short bf16x8;
typedef __attribute__((ext_vector_type(4))) float f32x4;

typedef const __attribute__((address_space(1))) void gvoid_t;
typedef __attribute__((address_space(3))) void lvoid_t;

#define FENCE asm volatile("" ::: "memory")
#define BAR()  do { FENCE; __builtin_amdgcn_s_barrier(); FENCE; } while (0)
#define GLD(src, dst) __builtin_amdgcn_global_load_lds((gvoid_t*)(src), (lvoid_t*)(dst), 16, 0, 0)

// fp32 -> bf16 RNE
__device__ __forceinline__ unsigned int f2bf(float f) {
  unsigned int u = __float_as_uint(f);
  return (u + 0x7fffu + ((u >> 16) & 1u)) >> 16;
}

// ---------------- fused prologue: cvt X -> bf16  |  expand iv -> dense bf16 W [N][K] ----------------
__global__ __launch_bounds__(256) void prep_kernel(const float* __restrict__ x,
                                                   const float* __restrict__ iv,
                                                   unsigned short* __restrict__ xb,
                                                   unsigned short* __restrict__ W) {
  int b = blockIdx.x;
  if (b < (M_DIM * K_DIM / 8) / 256) {
    int idx = b * 256 + threadIdx.x;          // one per 8 floats
    const float4* x4 = (const float4*)x;
    float4 a = x4[idx * 2 + 0];
    float4 c = x4[idx * 2 + 1];
    uint4 o;
    o.x = f2bf(a.x) | (f2bf(a.y) << 16);
    o.y = f2bf(a.z) | (f2bf(a.w) << 16);
    o.z = f2bf(c.x) | (f2bf(c.y) << 16);
    o.w = f2bf(c.z) | (f2bf(c.w) << 16);
    ((uint4*)xb)[idx] = o;
  } else {
    int idx = (b - (M_DIM * K_DIM / 8) / 256) * 256 + threadIdx.x;  // one per 8 weights
    int o  = idx >> 8;             // W row 0..2047
    int i0 = (idx & 255) * 8;      // col start
    int f = o >> 4, t = o & 15;
    int g = i0 >> 4, u0 = i0 & 15;
    const float* row = iv + (f * 128 + g) * 16;
    unsigned int p[4];
#pragma unroll
    for (int j = 0; j < 4; ++j) {
      unsigned int lo = f2bf(row[(t - (u0 + 2 * j + 0)) & 15]);
      unsigned int hi = f2bf(row[(t - (u0 + 2 * j + 1)) & 15]);
      p[j] = lo | (hi << 16);
    }
    ((uint4*)W)[idx] = make_uint4(p[0], p[1], p[2], p[3]);
  }
}

// ---------------- main GEMM ----------------
// LDS: 2 buffers of 32 KB: buf c at c*BUFSZ, A-part [128][128B], B-part at +16384.
// T2 XOR-swizzle byte ^= (row&7)<<4 on both the GLD global source and the ds_read col.
__global__ __launch_bounds__(256, 2) void gemm_bias_kernel(const unsigned short* __restrict__ A,
                                                           const unsigned short* __restrict__ B,
                                                           const float* __restrict__ bias,
                                                           float* __restrict__ C) {
  __shared__ char lds[2 * BUFSZ];   // 64 KB -> 2 blocks/CU

  const int tid = threadIdx.x;
  const int l   = tid & 63;
  const int w   = tid >> 6;       // wave 0..3
  const int wm  = w >> 1;         // wave row 0..1 (64 rows each)
  const int wn  = w & 1;          // wave col 0..1 (64 cols each)

  // T1: XCD-aware bijective swizzle (grid=512, 512%8==0; 64 consecutive per XCD
  // = 4 bm-panels x 16 bn -> A slice 2MB L2-resident)
  const int orig = blockIdx.x;
  const int swz  = (orig & 7) * 64 + (orig >> 3);
  const int bm   = swz >> 4;      // 0..31  (M tile)
  const int bn   = swz & 15;      // 0..15  (N tile)

  f32x4 acc[4][4] = {};

  // ---- staging addresses (inverse-swizzled global source, linear LDS dest) ----
  // GLD j (j=0..3) covers tile rows j*32 + w*8 + (l>>3); lane writes 16B slot (l&7).
  const int srow  = w * 8 + (l >> 3);               // 0..31
  const int sslot = (l & 7) ^ ((l >> 3) & 7);       // pre-swizzled K-slot
  const unsigned short* Asrc0 = A + (size_t)(bm * 128 + srow) * K_DIM + sslot * 8;
  const unsigned short* Bsrc0 = B + (size_t)(bn * 128 + srow) * K_DIM + sslot * 8;

  // ---- ds_read addresses (T2 swizzled) ----
  const int fr = l & 15;                            // fragment row within 16
  const int rxor = (l & 7) << 4;                    // (row&7)<<4
  const int aRow0 = (wm * 64 + fr) * 128;           // byte row base, + m*2048
  const int bRow0 = (wn * 64 + fr) * 128;           // + n*2048
  const int swzcol0 = (0 * 64 + (l >> 4) * 16) ^ rxor;  // K 0..31
  const int swzcol1 = (1 * 64 + (l >> 4) * 16) ^ rxor;  // K 32..63

  bf16x8 fa[4], fb[4];

  // stage tile T (A 4 GLD + B 4 GLD) into buffer BUFC
#define STAGE_AB(BUFC, T)                                               \
  do {                                                                  \
    char* ad_ = lds + (BUFC) * BUFSZ + w * 1024;                        \
    char* bd_ = ad_ + 16384;                                            \
    const unsigned short* as_ = Asrc0 + (T) * BK;                       \
    const unsigned short* bs_ = Bsrc0 + (T) * BK;                       \
    GLD(as_ + 0 * 32 * K_DIM, ad_ + 0);                                 \
    GLD(as_ + 1 * 32 * K_DIM, ad_ + 4096);                              \
    GLD(as_ + 2 * 32 * K_DIM, ad_ + 8192);                              \
    GLD(as_ + 3 * 32 * K_DIM, ad_ + 12288);                             \
    GLD(bs_ + 0 * 32 * K_DIM, bd_ + 0);                                 \
    GLD(bs_ + 1 * 32 * K_DIM, bd_ + 4096);                              \
    GLD(bs_ + 2 * 32 * K_DIM, bd_ + 8192);                              \
    GLD(bs_ + 3 * 32 * K_DIM, bd_ + 12288);                             \
  } while (0)

#define LDA(BUF, SWZ)                                                   \
  do {                                                                  \
    const char* Ab_ = lds + (BUF) * BUFSZ;                              \
    const char* Bb_ = Ab_ + 16384;                                      \
    _Pragma("unroll")                                                   \
    for (int m = 0; m < 4; ++m)                                         \
      fa[m] = *(const bf16x8*)(Ab_ + aRow0 + m * 2048 + (SWZ));         \
    _Pragma("unroll")                                                   \
    for (int n = 0; n < 4; ++n)                                         \
      fb[n] = *(const bf16x8*)(Bb_ + bRow0 + n * 2048 + (SWZ));         \
  } while (0)

#define MFMA_CLUSTER()                                                  \
  do {                                                                  \
    asm volatile("s_waitcnt lgkmcnt(0)" ::: "memory");                  \
    __builtin_amdgcn_sched_barrier(0);                                  \
    __builtin_amdgcn_s_setprio(1);                                      \
    _Pragma("unroll")                                                   \
    for (int m = 0; m < 4; ++m)                                         \
      _Pragma("unroll")                                                 \
      for (int n = 0; n < 4; ++n)                                       \
        acc[m][n] = __builtin_amdgcn_mfma_f32_16x16x32_bf16(fa[m], fb[n], acc[m][n], 0, 0, 0); \
    __builtin_amdgcn_s_setprio(0);                                      \
    __builtin_amdgcn_sched_barrier(0);                                  \
  } while (0)

  // Tile t: read CUR, stage t+1 into OTH (issued early, ~1 tile of flight),
  // one vmcnt(0)+BAR at tile end.
  // Safety: each wave's ds_reads retire at its lgkm(0) before it reaches BAR;
  // after BAR all waves' GLDs (OTH) have drained (per-wave vmcnt(0) precedes BAR).
#define BODY(T, CUR, OTH)                                               \
  do {                                                                  \
    LDA(CUR, swzcol0);                                                  \
    STAGE_AB(OTH, (T) + 1);                                             \
    MFMA_CLUSTER();                                                     \
    LDA(CUR, swzcol1);                                                  \
    MFMA_CLUSTER();                                                     \
    asm volatile("s_waitcnt vmcnt(0)" ::: "memory");                    \
    BAR();                                                              \
  } while (0)

  // ---- prologue: stage tile 0 ----
  STAGE_AB(0, 0);
  asm volatile("s_waitcnt vmcnt(0)" ::: "memory");
  BAR();

  // ---- main loop: tiles 0..29 (pairs for compile-time buffer indices) ----
  for (int t = 0; t < NT - 2; t += 2) {
    BODY(t + 0, 0, 1);
    BODY(t + 1, 1, 0);
  }
  // tile 30: stages tile 31 into buf 1
  BODY(30, 0, 1);
  // tile 31: no staging, no barriers needed
  LDA(1, swzcol0);
  MFMA_CLUSTER();
  LDA(1, swzcol1);
  MFMA_CLUSTER();

  // ---- epilogue: C/D layout col=lane&15, row=(lane>>4)*4+reg ----
  const int row0 = bm * 128 + wm * 64 + (l >> 4) * 4;
  const int col0 = bn * 128 + wn * 64 + (l & 15);
#pragma unroll
  for (int n = 0; n < 4; ++n) {
    float bv = bias[col0 + n * 16];
#pragma unroll
    for (int m = 0; m < 4; ++m) {
#pragma unroll
      for (int j = 0; j < 4; ++j) {
        C[(size_t)(row0 + m * 16 + j) * N_DIM + (col0 + n * 16)] = acc[m][n][j] + bv;
      }
    }
  }
#undef BODY
#undef MFMA_CLUSTER
#undef LDA
#undef STAGE_AB
}

// ---------------- fallback (ws too small): direct fp32 ----------------
__global__ __launch_bounds__(256) void fallback_kernel(const float* __restrict__ x,
                                                       const float* __restrict__ iv,
                                                       const float* __restrict__ b,
                                                       float* __restrict__ out) {
  int idx = blockIdx.x * 256 + threadIdx.x;
  int Bn = idx >> 11, o = idx & 2047;
  int f = o >> 4, t = o & 15;
  const float* xr = x + (size_t)Bn * 2048;
  float acc = 0.f;
  for (int g = 0; g < 128; ++g) {
    const float* pr = iv + (f * 128 + g) * 16;
    const float* xg = xr + g * 16;
#pragma unroll
    for (int s = 0; s < 16; ++s) acc += pr[s] * xg[(t - s) & 15];
  }
  out[idx] = acc + b[o];
}

extern "C" void kernel_launch(void* const* d_in, const int* in_sizes, int n_in,
                              void* d_out, int out_size, void* d_ws, size_t ws_size,
                              hipStream_t stream) {
  const float* x    = (const float*)d_in[0];
  const float* iv   = (const float*)d_in[1];
  const float* bias = (const float*)d_in[2];
  float* out = (float*)d_out;

  const size_t xb_bytes = (size_t)M_DIM * K_DIM * 2;
  const size_t w_bytes  = (size_t)N_DIM * K_DIM * 2;
  if (ws_size < xb_bytes + w_bytes) {
    fallback_kernel<<<(M_DIM * N_DIM) / 256, 256, 0, stream>>>(x, iv, bias, out);
    return;
  }

  unsigned short* xb = (unsigned short*)d_ws;
  unsigned short* W  = xb + (size_t)M_DIM * K_DIM;

  const int cvt_blocks = (M_DIM * K_DIM / 8) / 256;   // 4096
  const int bw_blocks  = (N_DIM * K_DIM / 8) / 256;   // 2048
  prep_kernel<<<cvt_blocks + bw_blocks, 256, 0, stream>>>(x, iv, xb, W);

  gemm_bias_kernel<<<(M_DIM / 128) * (N_DIM / 128), 256, 0, stream>>>(xb, W, bias, out);
}